// Round 9
// baseline (33.621 us; speedup 1.0000x reference)
//
#include <hip/hip_runtime.h>

// LocallyConnected2d: out[b,o,ho,wo] = bias[o,ho,wo]
//   + sum_{c,ki,kj} x[b,c,ho+ki,wo+kj] * w[o,c,ho,wo,ki*3+kj]
//
// Round-9: ELIMINATE the LDS weight path entirely.
//   r5(barrier)==r7(vmcnt A)==r8(vmcnt B)==26.6us -> limit is pipe
//   throughput, not sync. Suspect: LSU front-end shared by VMEM + LDSDMA +
//   DS. Each lane's 36 weight floats are CONTIGUOUS in global memory ->
//   load direct to VGPRs (9x dwordx4), deleting 9 glds + 9 ds_read_b128
//   per body and ALL staging sync. LDS keeps only the 8KB epilogue stash.
//  - lane (q,l): q=lane>>4 owns b=2q,2q+1; l=lane&15 owns 4 wo.
//    Lane 15 clamped to colbase=58 (wo 58..61): keeps every weight/x read
//    in-bounds for ALL blocks (unclamped lane 15 reads 18 floats past the
//    tensor end at the last (o,c,ho)). Lanes 14/15 both compute wo 58/59
//    with bit-identical operation order -> benign identical stash overlap.
//  - aligned(4) vector typedefs: colbase=58 makes f4/f2 only 8B-aligned.
//  - #pragma unroll 1 on the c-loop: keeps VGPR ~90 (no 4-body hoist).

#define BB 8
#define CC 16
#define HH 64
#define WW 64
#define OO 32
#define HO 62
#define WO 62
#define NLOC (HO * WO)    // 3844
#define TOTAL (OO * NLOC) // 123008

typedef float f4 __attribute__((ext_vector_type(4)));
typedef float f2 __attribute__((ext_vector_type(2)));
typedef float f4u __attribute__((ext_vector_type(4), aligned(4)));
typedef float f2u __attribute__((ext_vector_type(2), aligned(4)));

__global__ __launch_bounds__(256) void lc2d_kernel(
    const float* __restrict__ x, const float* __restrict__ weight,
    const float* __restrict__ bias, float* __restrict__ out) {
  __shared__ __align__(16) float smem[4 * 512];  // stash: [wave][b(8)][64]

  const int tid  = threadIdx.x;
  const int lane = tid & 63;
  const int wave = tid >> 6;
  const int l = lane & 15;   // wo-group
  const int q = lane >> 4;   // b-group: b = 2q, 2q+1
  const int ho = blockIdx.x % HO;
  const int o  = blockIdx.x / HO;

  const int colbase = (l < 15) ? 4 * l : 58;  // lane 15 clamped (see header)

  // per-lane weight base: (o, c=wave*4, ho, colbase, 0) — 36 contiguous floats
  const float* wl = weight + ((size_t)(o * CC + wave * 4) * NLOC
                              + (size_t)(ho * WO + colbase)) * 9;

  f4 acc[2];
  acc[0] = (f4)0.f;
  acc[1] = (f4)0.f;

#pragma unroll 1
  for (int cc = 0; cc < 4; ++cc) {
    const float* wp = wl + (size_t)cc * (NLOC * 9);
    // ---- 36 weights straight to VGPRs: 9x global dwordx4 ----
    f4 wq[9];
#pragma unroll
    for (int k = 0; k < 9; ++k)
      wq[k] = *(const f4u*)(wp + 4 * k);

    const int c = wave * 4 + cc;
#pragma unroll
    for (int bo = 0; bo < 2; ++bo) {
      const float* xb = x + ((size_t)(2 * q + bo) * CC + c) * (HH * WW)
                          + (size_t)ho * WW + colbase;
      f4 v4[3];
      f2 v2[3];
#pragma unroll
      for (int r = 0; r < 3; ++r) {
        v4[r] = *(const f4u*)(xb + r * WW);
        v2[r] = *(const f2u*)(xb + r * WW + 4);
      }
#pragma unroll
      for (int w4 = 0; w4 < 4; ++w4) {
        float s = 0.f;
#pragma unroll
        for (int r = 0; r < 3; ++r) {
#pragma unroll
          for (int j = 0; j < 3; ++j) {
            const int e = w4 + j;                 // 0..5, compile-time
            const int wi = w4 * 9 + r * 3 + j;    // 0..35, compile-time
            const float xv = (e < 4) ? v4[r][e] : v2[r][e - 4];
            s += xv * wq[wi >> 2][wi & 3];
          }
        }
        acc[bo][w4] += s;
      }
    }
  }

  // ---- stash partials (lane 14/15 overlap writes identical values) ----
#pragma unroll
  for (int bo = 0; bo < 2; ++bo)
    *(f4u*)(smem + wave * 512 + (2 * q + bo) * 64 + colbase) = acc[bo];
  __syncthreads();  // the only block-wide barrier

  // ---- reduce 4 wave-partials, add bias, coalesced store ----
  for (int p = tid; p < 512; p += 256) {
    const int b  = p >> 6;
    const int wo = p & 63;
    if (wo < WO) {
      float s = smem[0 * 512 + p] + smem[1 * 512 + p]
              + smem[2 * 512 + p] + smem[3 * 512 + p];
      const int loc = o * NLOC + ho * WO + wo;
      out[(size_t)b * TOTAL + loc] = s + bias[loc];
    }
  }
}

extern "C" void kernel_launch(void* const* d_in, const int* in_sizes, int n_in,
                              void* d_out, int out_size, void* d_ws, size_t ws_size,
                              hipStream_t stream) {
  const float* x = (const float*)d_in[0];
  const float* w = (const float*)d_in[1];
  const float* bias = (const float*)d_in[2];
  float* out = (float*)d_out;

  hipLaunchKernelGGL(lc2d_kernel, dim3(OO * HO), dim3(256), 0, stream,
                     x, w, bias, out);
}

// Round 10
// 26.224 us; speedup vs baseline: 1.2821x; 1.2821x over previous
//
#include <hip/hip_runtime.h>

// LocallyConnected2d: out[b,o,ho,wo] = bias[o,ho,wo]
//   + sum_{c,ki,kj} x[b,c,ho+ki,wo+kj] * w[o,c,ho,wo,ki*3+kj]
//
// Round-10 = Round-8 with ONLY the staging width changed: 9x width-4
// global_load_lds -> 2x width-16 + 1x width-4 tail per weight row.
//   Rationale: guide m193 A/B: glds width 4->16 = +67% (per-instruction DMA
//   cost dominates staging). r5-r8 all used 9 width-4 DMAs/body -> invariant
//   ~26.6us regardless of sync scheme. r9's line-rate model (validated by
//   its +7us scatter regression) puts known pipes at ~11-13us; the DMA
//   per-instr cost is the unmodeled remainder.
// Staging (558 floats): instr0 floats 0..255 (w16), instr1 256..511 (w16),
//   instr2 512..557 (w4, lane<46 — always issues, exact bounds, no OOB).
// vmcnt: queue/body = [stage(cc):3][x(cc):12][stage(cc+1):3] -> vmcnt(15)
//   drains exactly stage(cc), leaves x+next stage in flight. Body3: vmcnt(12).
// Everything else identical to r8 (lane (q,l) mapping, 9x ds_read_b128,
// sched_barrier group pinning, single epilogue barrier + reduce).

#define BB 8
#define CC 16
#define HH 64
#define WW 64
#define OO 32
#define HO 62
#define WO 62
#define NLOC (HO * WO)    // 3844
#define TOTAL (OO * NLOC) // 123008

typedef float f4 __attribute__((ext_vector_type(4)));
typedef float f2 __attribute__((ext_vector_type(2)));

__device__ __forceinline__ void async_f32_to_lds(const float* g, float* l) {
  __builtin_amdgcn_global_load_lds((const __attribute__((address_space(1))) void*)g,
                                   (__attribute__((address_space(3))) void*)l,
                                   4, 0, 0);
}
__device__ __forceinline__ void async_f32x4_to_lds(const float* g, float* l) {
  __builtin_amdgcn_global_load_lds((const __attribute__((address_space(1))) void*)g,
                                   (__attribute__((address_space(3))) void*)l,
                                   16, 0, 0);
}

__global__ __launch_bounds__(256) void lc2d_kernel(
    const float* __restrict__ x, const float* __restrict__ weight,
    const float* __restrict__ bias, float* __restrict__ out) {
  // per wave: two 576-float weight buffers; buf0 reused for partial stash
  __shared__ __align__(16) float smem[4 * 2 * 576];

  const int tid  = threadIdx.x;
  const int lane = tid & 63;
  const int wave = tid >> 6;
  const int l = lane & 15;   // wo-group: wo = 4l..4l+3
  const int q = lane >> 4;   // b-group:  b  = 2q, 2q+1
  const int ho = blockIdx.x % HO;
  const int o  = blockIdx.x / HO;

  float* buf0 = smem + wave * 1152;

  const int colbase = 4 * l;
  const int f2off = (l < 15) ? 4 : -4;  // l=15: dummy in-bounds read, discarded

  const float* wbase = weight + (size_t)(o * CC + wave * 4) * (NLOC * 9)
                              + (size_t)ho * (WO * 9);

  // ---- stage one 558-float weight row: 2x w16 DMA + 1x w4 tail ----
#define STAGE(SRC, DST)                                              \
  {                                                                  \
    async_f32x4_to_lds((SRC) + lane * 4, (DST));                     \
    async_f32x4_to_lds((SRC) + 256 + lane * 4, (DST) + 256);         \
    if (lane < 46) async_f32_to_lds((SRC) + 512 + lane, (DST) + 512);\
  }

  // ---- prologue: stage cc=0 into buf0 (3 VMEM) ----
  STAGE(wbase, buf0)

  f4 acc[2];
  acc[0] = (f4)0.f;
  acc[1] = (f4)0.f;

#pragma unroll
  for (int cc = 0; cc < 4; ++cc) {
    const float* cur = buf0 + (cc & 1) * 576;
    float* nxt = buf0 + ((cc + 1) & 1) * 576;
    const int c = wave * 4 + cc;

    __builtin_amdgcn_sched_barrier(0);
    // ---- group 1: ALL x loads for this body (12 VMEM) ----
    f4 v4[2][3];
    f2 v2[2][3];
#pragma unroll
    for (int bo = 0; bo < 2; ++bo) {
      const float* xb = x + ((size_t)(2 * q + bo) * CC + c) * (HH * WW)
                          + (size_t)ho * WW + colbase;
#pragma unroll
      for (int r = 0; r < 3; ++r) {
        v4[bo][r] = *(const f4*)(xb + r * WW);
        v2[bo][r] = *(const f2*)(xb + r * WW + f2off);
      }
    }
    __builtin_amdgcn_sched_barrier(0);
    // ---- group 2: issue stage(cc+1) (3 VMEM) ----
    if (cc < 3) {
      const float* wg = wbase + (size_t)(cc + 1) * (NLOC * 9);
      STAGE(wg, nxt)
    }
    __builtin_amdgcn_sched_barrier(0);
    // ---- group 3: drain stage(cc); x + stage(cc+1) stay in flight ----
    if (cc < 3) {
      asm volatile("s_waitcnt vmcnt(15)");
    } else {
      asm volatile("s_waitcnt vmcnt(12)");
    }
    __builtin_amdgcn_sched_barrier(0);

    // ---- group 4: weights from LDS + FMAs ----
    f4 wq[9];
#pragma unroll
    for (int k = 0; k < 9; ++k)
      wq[k] = *(const f4*)(cur + 36 * l + 4 * k);

#pragma unroll
    for (int bo = 0; bo < 2; ++bo) {
#pragma unroll
      for (int w4 = 0; w4 < 4; ++w4) {
        float s = 0.f;
#pragma unroll
        for (int r = 0; r < 3; ++r) {
#pragma unroll
          for (int j = 0; j < 3; ++j) {
            const int e = w4 + j;                 // 0..5, compile-time
            const int wi = w4 * 9 + r * 3 + j;    // 0..35, compile-time
            const float xv = (e < 4) ? v4[bo][r][e] : v2[bo][r][e - 4];
            s += xv * wq[wi >> 2][wi & 3];
          }
        }
        acc[bo][w4] += s;
      }
    }
  }
#undef STAGE

  // ---- stash partials into this wave's buf0 (stage(3) -> buf1 drained at
  // body3's vmcnt(12); stash ordered after wq reads by data dependence) ----
#pragma unroll
  for (int bo = 0; bo < 2; ++bo)
    *(f4*)(buf0 + (2 * q + bo) * 64 + colbase) = acc[bo];
  __syncthreads();  // the only block-wide barrier

  // ---- reduce 4 wave-partials, add bias, coalesced store ----
  for (int p = tid; p < 512; p += 256) {
    const int b  = p >> 6;
    const int wo = p & 63;
    if (wo < WO) {
      float s = smem[0 * 1152 + p] + smem[1 * 1152 + p]
              + smem[2 * 1152 + p] + smem[3 * 1152 + p];
      const int loc = o * NLOC + ho * WO + wo;
      out[(size_t)b * TOTAL + loc] = s + bias[loc];
    }
  }
}

extern "C" void kernel_launch(void* const* d_in, const int* in_sizes, int n_in,
                              void* d_out, int out_size, void* d_ws, size_t ws_size,
                              hipStream_t stream) {
  const float* x = (const float*)d_in[0];
  const float* w = (const float*)d_in[1];
  const float* bias = (const float*)d_in[2];
  float* out = (float*)d_out;

  hipLaunchKernelGGL(lc2d_kernel, dim3(OO * HO), dim3(256), 0, stream,
                     x, w, bias, out);
}